// Round 3
// baseline (235.276 us; speedup 1.0000x reference)
//
#include <hip/hip_runtime.h>
#include <hip/hip_bf16.h>
#include <stdint.h>

// B=4096, H=256, K=16, D=512 (8*64)
#define NB   4096
#define NH   256
#define NK   16
#define ND   512

using short8  = __attribute__((ext_vector_type(8))) short;
using float4v = __attribute__((ext_vector_type(4))) float;

__device__ __forceinline__ float fast_tanh(float x) {
  float e = __builtin_amdgcn_exp2f(x * 2.88539008177793f);
  return 1.0f - 2.0f * __builtin_amdgcn_rcpf(e + 1.0f);
}

__device__ __forceinline__ unsigned short f2bf(float f) {
  union { float f; unsigned u; } v; v.f = f;
  unsigned r = v.u + 0x7FFF + ((v.u >> 16) & 1);  // RNE, inputs finite
  return (unsigned short)(r >> 16);
}

__device__ __forceinline__ float bf2f(unsigned short h) {
  union { unsigned u; float f; } v; v.u = ((unsigned)h) << 16; return v.f;
}

// ------------------------------------------------------------- fused prep ----
// blocks [0,16384): h1 -> A2[k][kk][b][32] (K-major tiles, bf16)
// blocks [16384,17408): w2 -> B2[k][kk][e][32] (transposed K-major, bf16)
// blocks [17408,17920): gating softmax
__global__ __launch_bounds__(256) void k_prep(
    const float* __restrict__ x_ext, const float* __restrict__ w1,
    const float* __restrict__ b1, const float* __restrict__ w2,
    const float* __restrict__ h_prev, const float* __restrict__ gw1,
    const float* __restrict__ gb1, const float* __restrict__ gw2,
    const float* __restrict__ gb2,
    unsigned short* __restrict__ A2, unsigned short* __restrict__ B2,
    float* __restrict__ gates) {
  __shared__ float sbuf[4160];  // w2t: [64][65]; gates: sh_h 2048 + sh_t 2048
  const int t = threadIdx.x;
  const int lin = blockIdx.x;

  if (lin < 16384) {
    // ---- h1: A2[((k*16+kk)*4096 + b)*32 + c] = tanh(x*w1+b1) ----
    const int gid = lin * 256 + t;
    const int c8 = (gid & 3) * 8;
    const int b  = (gid >> 2) & (NB - 1);
    const int kk = (gid >> 14) & 15;
    const int k  = gid >> 18;
    const int d  = kk * 32 + c8;
    const float x = x_ext[b * NK + k];
    const float4 wlo = *(const float4*)&w1[k * ND + d];
    const float4 whi = *(const float4*)&w1[k * ND + d + 4];
    const float4 blo = *(const float4*)&b1[k * ND + d];
    const float4 bhi = *(const float4*)&b1[k * ND + d + 4];
    unsigned short o[8];
    o[0] = f2bf(fast_tanh(x * wlo.x + blo.x));
    o[1] = f2bf(fast_tanh(x * wlo.y + blo.y));
    o[2] = f2bf(fast_tanh(x * wlo.z + blo.z));
    o[3] = f2bf(fast_tanh(x * wlo.w + blo.w));
    o[4] = f2bf(fast_tanh(x * whi.x + bhi.x));
    o[5] = f2bf(fast_tanh(x * whi.y + bhi.y));
    o[6] = f2bf(fast_tanh(x * whi.z + bhi.z));
    o[7] = f2bf(fast_tanh(x * whi.w + bhi.w));
    *(uint4*)&A2[(((size_t)(k * 16 + kk)) * NB + b) * 32 + c8] = *(uint4*)o;
  } else if (lin < 17408) {
    // ---- w2 transpose: B2[((k*16+kk)*512 + e)*32 + c] = w2[k][kk*32+c][e] ----
    const int w = lin - 16384;
    const int e0 = (w & 7) * 64;
    const int d0 = ((w >> 3) & 7) * 64;
    const int k = w >> 6;
    float (*sh)[65] = (float(*)[65])sbuf;
    const float* src = w2 + ((size_t)k * ND + d0) * ND + e0;
#pragma unroll
    for (int rep = 0; rep < 4; ++rep) {
      int r = rep * 16 + (t >> 4);
      int c = (t & 15) * 4;
      float4 v = *(const float4*)&src[(size_t)r * ND + c];
      sh[r][c] = v.x; sh[r][c + 1] = v.y; sh[r][c + 2] = v.z; sh[r][c + 3] = v.w;
    }
    __syncthreads();
#pragma unroll
    for (int s = 0; s < 2; ++s) {
      int idx = t + s * 256;
      int kh = idx >> 8;            // which 32-wide d-chunk
      int rem = idx & 255;
      int e = e0 + (rem >> 2);
      int c8 = (rem & 3) * 8;
      int kk = (d0 >> 5) + kh;
      unsigned short o[8];
#pragma unroll
      for (int j = 0; j < 8; ++j) o[j] = f2bf(sh[kh * 32 + c8 + j][e - e0]);
      *(uint4*)&B2[(((size_t)(k * 16 + kk)) * ND + e) * 32 + c8] = *(uint4*)o;
    }
  } else {
    // ---- gating ----
    const int b0 = (lin - 17408) * 8;
    float* sh_h = sbuf;            // [8][256]
    float* sh_t = sbuf + 2048;     // [256][8]
    for (int r = 0; r < 8; ++r) sh_h[r * 256 + t] = h_prev[(b0 + r) * NH + t];
    __syncthreads();
    float acc[8];
    float bias = gb1[t];
#pragma unroll
    for (int r = 0; r < 8; ++r) acc[r] = bias;
    for (int i = 0; i < NH; i += 4) {
      float w0 = gw1[(i + 0) * NH + t];
      float w1v = gw1[(i + 1) * NH + t];
      float w2v = gw1[(i + 2) * NH + t];
      float w3 = gw1[(i + 3) * NH + t];
#pragma unroll
      for (int r = 0; r < 8; ++r) {
        float4 hv = *(const float4*)&sh_h[r * 256 + i];
        acc[r] += hv.x * w0 + hv.y * w1v + hv.z * w2v + hv.w * w3;
      }
    }
#pragma unroll
    for (int r = 0; r < 8; ++r) sh_t[t * 8 + r] = fast_tanh(acc[r]);
    __syncthreads();
    if (t < 128) {
      const int r = t >> 4, k = t & 15;
      float lg = gb2[k];
      for (int j = 0; j < NH; ++j) lg += sh_t[j * 8 + r] * gw2[j * NK + k];
      float m = lg;
      for (int off = 1; off < 16; off <<= 1) m = fmaxf(m, __shfl_xor(m, off, 16));
      float e = __builtin_amdgcn_exp2f((lg - m) * 1.44269504f);
      float s = e;
      for (int off = 1; off < 16; off <<= 1) s += __shfl_xor(s, off, 16);
      gates[(b0 + r) * NK + k] = e * __builtin_amdgcn_rcpf(s);
    }
  }
}

// ------------------------------------------------------------------ GEMM ----
// Direct-to-register, zero-LDS K-loop. A2/B2 are K-major tiled so every
// fragment load is a wave-contiguous 1KB global_load_dwordx4. Ping-pong
// prefetch; no barriers in the K-loop -> compiler emits fine-grained vmcnt.
__global__ __launch_bounds__(256) void k_gemm(
    const unsigned short* __restrict__ A2,    // [K*16][4096][32]
    const unsigned short* __restrict__ B2,    // [K*16][512][32]
    const float* __restrict__ b2,             // [K][512]
    unsigned short* __restrict__ h2bf) {      // [K][B][512]
  __shared__ __align__(16) unsigned short sh2[128 * 128];  // 32 KB epilogue
  const int t = threadIdx.x;
  const int l = t & 63;
  const int w = t >> 6;
  // XCD swizzle: 2 experts per XCD; n fastest for A-tile L2 reuse
  const int lin = blockIdx.x;
  const int xcd = lin & 7;
  const int slot = lin >> 3;                 // 0..255
  const int ke = xcd * 2 + (slot >> 7);      // 0..15
  const int mn = slot & 127;
  const int m0 = (mn >> 2) << 7;             // 32 m-blocks
  const int n0 = (mn & 3) << 7;              // 4 n-blocks

  const int wm = w & 1, wn = w >> 1;
  const int q = l >> 4, m16 = l & 15;

  const unsigned short* Abase =
      A2 + (((size_t)(ke * 16)) * NB + m0 + wm * 64 + m16) * 32 + q * 8;
  const unsigned short* Bbase =
      B2 + (((size_t)(ke * 16)) * ND + n0 + wn * 64 + m16) * 32 + q * 8;

  float4v acc[4][4];
#pragma unroll
  for (int a = 0; a < 4; ++a)
#pragma unroll
    for (int b = 0; b < 4; ++b) acc[a][b] = (float4v){0.f, 0.f, 0.f, 0.f};

  short8 fa[2][4], fb[2][4];
#pragma unroll
  for (int i = 0; i < 4; ++i) {
    fa[0][i] = *(const short8*)(Abase + (size_t)i * 512);
    fb[0][i] = *(const short8*)(Bbase + (size_t)i * 512);
  }
#pragma unroll
  for (int kk = 0; kk < 16; ++kk) {
    const int cur = kk & 1, nxt = cur ^ 1;
    if (kk < 15) {
      const unsigned short* Ap = Abase + (size_t)(kk + 1) * (NB * 32);
      const unsigned short* Bp = Bbase + (size_t)(kk + 1) * (ND * 32);
#pragma unroll
      for (int i = 0; i < 4; ++i) {
        fa[nxt][i] = *(const short8*)(Ap + (size_t)i * 512);
        fb[nxt][i] = *(const short8*)(Bp + (size_t)i * 512);
      }
    }
#pragma unroll
    for (int a = 0; a < 4; ++a)
#pragma unroll
      for (int b = 0; b < 4; ++b)
        acc[a][b] = __builtin_amdgcn_mfma_f32_16x16x32_bf16(fa[cur][a], fb[cur][b], acc[a][b], 0, 0, 0);
  }

  // epilogue: +b2, tanh, bf16 via LDS transpose, coalesced uint4 stores.
  const float* b2k = b2 + ke * ND;
#pragma unroll
  for (int bni = 0; bni < 4; ++bni) {
    int lc = wn * 64 + bni * 16 + m16;
    float bias = b2k[n0 + lc];
#pragma unroll
    for (int ami = 0; ami < 4; ++ami) {
      int lr = wm * 64 + ami * 16 + q * 4;
#pragma unroll
      for (int rr = 0; rr < 4; ++rr)
        sh2[(lr + rr) * 128 + lc] = f2bf(fast_tanh(acc[ami][bni][rr] + bias));
    }
  }
  __syncthreads();
  unsigned short* Ob = h2bf + ((size_t)ke * NB + m0) * ND + n0;
#pragma unroll
  for (int r8 = 0; r8 < 8; ++r8) {
    int idx = r8 * 256 + t;
    int row = idx >> 4;            // 128 rows
    int c16 = (idx & 15) * 8;      // 16 x 8 = 128 cols
    *(uint4*)&Ob[(size_t)row * ND + c16] = *(uint4*)&sh2[row * 128 + c16];
  }
}

// -------------------------------------------------- LN + gate-mix + final ----
__global__ __launch_bounds__(256) void k_final(
    const unsigned short* __restrict__ h2bf,  // [K][B][512]
    const float* __restrict__ gates,          // [B][16]
    const float* __restrict__ x_l,            // [B][8]
    const float* __restrict__ ln_g, const float* __restrict__ ln_b,
    const float* __restrict__ theta0,         // [512]
    float* __restrict__ out) {
  const int t = threadIdx.x;
  const int l = t & 63;
  const int b = blockIdx.x * 4 + (t >> 6);
  const int d0 = l * 8;
  float g[8], bb[8], t0[8], acc[8];
  *(float4*)&g[0] = *(const float4*)&ln_g[d0];
  *(float4*)&g[4] = *(const float4*)&ln_g[d0 + 4];
  *(float4*)&bb[0] = *(const float4*)&ln_b[d0];
  *(float4*)&bb[4] = *(const float4*)&ln_b[d0 + 4];
  *(float4*)&t0[0] = *(const float4*)&theta0[d0];
  *(float4*)&t0[4] = *(const float4*)&theta0[d0 + 4];
#pragma unroll
  for (int j = 0; j < 8; ++j) acc[j] = 0.f;
  const float xl = x_l[b * 8 + (l >> 3)];

  for (int k = 0; k < NK; ++k) {
    uint4 raw = *(const uint4*)&h2bf[((size_t)k * NB + b) * ND + d0];
    const unsigned short* hp = (const unsigned short*)&raw;
    float v[8];
#pragma unroll
    for (int j = 0; j < 8; ++j) v[j] = bf2f(hp[j]);
    float s = 0.f, s2 = 0.f;
#pragma unroll
    for (int j = 0; j < 8; ++j) { s += v[j]; s2 += v[j] * v[j]; }
    for (int off = 1; off < 64; off <<= 1) {
      s += __shfl_xor(s, off, 64);
      s2 += __shfl_xor(s2, off, 64);
    }
    float mu = s * (1.f / 512.f);
    float var = s2 * (1.f / 512.f) - mu * mu;
    float rs = __builtin_amdgcn_rsqf(var + 1e-5f);
    float gate = gates[b * NK + k];
#pragma unroll
    for (int j = 0; j < 8; ++j) acc[j] += gate * ((v[j] - mu) * rs * g[j] + bb[j]);
  }
  float th[8];
#pragma unroll
  for (int j = 0; j < 8; ++j) th[j] = acc[j] + t0[j];
  float* thp = out + (size_t)NB * 64 + (size_t)b * ND + d0;
  *(float4*)&thp[0] = *(float4*)&th[0];
  *(float4*)&thp[4] = *(float4*)&th[4];
  float p[8];
#pragma unroll
  for (int j = 0; j < 8; ++j) p[j] = xl * th[j];
  for (int off = 8; off < 64; off <<= 1)
#pragma unroll
    for (int j = 0; j < 8; ++j) p[j] += __shfl_xor(p[j], off, 64);
  if (l < 8) {
    float* xp = out + (size_t)b * 64 + l * 8;
    *(float4*)&xp[0] = *(float4*)&p[0];
    *(float4*)&xp[4] = *(float4*)&p[4];
  }
}

// ----------------------------------------------------------------- launch ----
extern "C" void kernel_launch(void* const* d_in, const int* in_sizes, int n_in,
                              void* d_out, int out_size, void* d_ws, size_t ws_size,
                              hipStream_t stream) {
  const float* h_prev = (const float*)d_in[0];
  const float* x_l    = (const float*)d_in[1];
  const float* x_ext  = (const float*)d_in[2];
  const float* mw1    = (const float*)d_in[3];
  const float* mb1    = (const float*)d_in[4];
  const float* mw2    = (const float*)d_in[5];
  const float* mb2    = (const float*)d_in[6];
  const float* gw1    = (const float*)d_in[7];
  const float* gb1    = (const float*)d_in[8];
  const float* gw2    = (const float*)d_in[9];
  const float* gb2    = (const float*)d_in[10];
  const float* ln_g   = (const float*)d_in[11];
  const float* ln_b   = (const float*)d_in[12];
  const float* th0    = (const float*)d_in[13];
  float* out = (float*)d_out;

  char* ws = (char*)d_ws;
  float* gates = (float*)ws;                                   // 256 KB
  unsigned short* A2 = (unsigned short*)(ws + (1u << 18));     // 64 MB
  unsigned short* B2 = (unsigned short*)(ws + (1u << 18) + (64u << 20));  // 8 MB
  unsigned short* h2bf = (unsigned short*)(ws + (1u << 18) + (72u << 20));  // 64 MB

  hipLaunchKernelGGL(k_prep, dim3(17920), dim3(256), 0, stream,
                     x_ext, mw1, mb1, mw2, h_prev, gw1, gb1, gw2, gb2,
                     A2, B2, gates);
  hipLaunchKernelGGL(k_gemm, dim3(2048), dim3(256), 0, stream,
                     A2, B2, mb2, h2bf);
  hipLaunchKernelGGL(k_final, dim3(NB / 4), dim3(256), 0, stream,
                     h2bf, gates, x_l, ln_g, ln_b, th0, out);
}

// Round 4
// 204.631 us; speedup vs baseline: 1.1498x; 1.1498x over previous
//
#include <hip/hip_runtime.h>
#include <hip/hip_bf16.h>
#include <stdint.h>

// B=4096, H=256, K=16, D=512 (8*64)
#define NB   4096
#define NH   256
#define NK   16
#define ND   512

using short8  = __attribute__((ext_vector_type(8))) short;
using float4v = __attribute__((ext_vector_type(4))) float;

__device__ __forceinline__ float fast_tanh(float x) {
  float e = __builtin_amdgcn_exp2f(x * 2.88539008177793f);
  return 1.0f - 2.0f * __builtin_amdgcn_rcpf(e + 1.0f);
}

__device__ __forceinline__ unsigned short f2bf(float f) {
  union { float f; unsigned u; } v; v.f = f;
  unsigned r = v.u + 0x7FFF + ((v.u >> 16) & 1);  // RNE, inputs finite
  return (unsigned short)(r >> 16);
}

__device__ __forceinline__ float bf2f(unsigned short h) {
  union { unsigned u; float f; } v; v.u = ((unsigned)h) << 16; return v.f;
}

// ------------------------------------------------------------- fused prep ----
// blocks [0,16384): h1 -> A2[k][kk][b][32] (K-major tiles, bf16)
// blocks [16384,17408): w2 -> B2[k][kk][e][32] (transposed K-major, bf16)
// blocks [17408,17920): gating softmax
__global__ __launch_bounds__(256) void k_prep(
    const float* __restrict__ x_ext, const float* __restrict__ w1,
    const float* __restrict__ b1, const float* __restrict__ w2,
    const float* __restrict__ h_prev, const float* __restrict__ gw1,
    const float* __restrict__ gb1, const float* __restrict__ gw2,
    const float* __restrict__ gb2,
    unsigned short* __restrict__ A2, unsigned short* __restrict__ B2,
    float* __restrict__ gates) {
  __shared__ float sbuf[4160];  // w2t: [64][65]; gates: sh_h 2048 + sh_t 2048
  const int t = threadIdx.x;
  const int lin = blockIdx.x;

  if (lin < 16384) {
    const int gid = lin * 256 + t;
    const int c8 = (gid & 3) * 8;
    const int b  = (gid >> 2) & (NB - 1);
    const int kk = (gid >> 14) & 15;
    const int k  = gid >> 18;
    const int d  = kk * 32 + c8;
    const float x = x_ext[b * NK + k];
    const float4 wlo = *(const float4*)&w1[k * ND + d];
    const float4 whi = *(const float4*)&w1[k * ND + d + 4];
    const float4 blo = *(const float4*)&b1[k * ND + d];
    const float4 bhi = *(const float4*)&b1[k * ND + d + 4];
    unsigned short o[8];
    o[0] = f2bf(fast_tanh(x * wlo.x + blo.x));
    o[1] = f2bf(fast_tanh(x * wlo.y + blo.y));
    o[2] = f2bf(fast_tanh(x * wlo.z + blo.z));
    o[3] = f2bf(fast_tanh(x * wlo.w + blo.w));
    o[4] = f2bf(fast_tanh(x * whi.x + bhi.x));
    o[5] = f2bf(fast_tanh(x * whi.y + bhi.y));
    o[6] = f2bf(fast_tanh(x * whi.z + bhi.z));
    o[7] = f2bf(fast_tanh(x * whi.w + bhi.w));
    *(uint4*)&A2[(((size_t)(k * 16 + kk)) * NB + b) * 32 + c8] = *(uint4*)o;
  } else if (lin < 17408) {
    const int w = lin - 16384;
    const int e0 = (w & 7) * 64;
    const int d0 = ((w >> 3) & 7) * 64;
    const int k = w >> 6;
    float (*sh)[65] = (float(*)[65])sbuf;
    const float* src = w2 + ((size_t)k * ND + d0) * ND + e0;
#pragma unroll
    for (int rep = 0; rep < 4; ++rep) {
      int r = rep * 16 + (t >> 4);
      int c = (t & 15) * 4;
      float4 v = *(const float4*)&src[(size_t)r * ND + c];
      sh[r][c] = v.x; sh[r][c + 1] = v.y; sh[r][c + 2] = v.z; sh[r][c + 3] = v.w;
    }
    __syncthreads();
#pragma unroll
    for (int s = 0; s < 2; ++s) {
      int idx = t + s * 256;
      int kh = idx >> 8;
      int rem = idx & 255;
      int e = e0 + (rem >> 2);
      int c8 = (rem & 3) * 8;
      int kk = (d0 >> 5) + kh;
      unsigned short o[8];
#pragma unroll
      for (int j = 0; j < 8; ++j) o[j] = f2bf(sh[kh * 32 + c8 + j][e - e0]);
      *(uint4*)&B2[(((size_t)(k * 16 + kk)) * ND + e) * 32 + c8] = *(uint4*)o;
    }
  } else {
    const int b0 = (lin - 17408) * 8;
    float* sh_h = sbuf;
    float* sh_t = sbuf + 2048;
    for (int r = 0; r < 8; ++r) sh_h[r * 256 + t] = h_prev[(b0 + r) * NH + t];
    __syncthreads();
    float acc[8];
    float bias = gb1[t];
#pragma unroll
    for (int r = 0; r < 8; ++r) acc[r] = bias;
    for (int i = 0; i < NH; i += 4) {
      float w0 = gw1[(i + 0) * NH + t];
      float w1v = gw1[(i + 1) * NH + t];
      float w2v = gw1[(i + 2) * NH + t];
      float w3 = gw1[(i + 3) * NH + t];
#pragma unroll
      for (int r = 0; r < 8; ++r) {
        float4 hv = *(const float4*)&sh_h[r * 256 + i];
        acc[r] += hv.x * w0 + hv.y * w1v + hv.z * w2v + hv.w * w3;
      }
    }
#pragma unroll
    for (int r = 0; r < 8; ++r) sh_t[t * 8 + r] = fast_tanh(acc[r]);
    __syncthreads();
    if (t < 128) {
      const int r = t >> 4, k = t & 15;
      float lg = gb2[k];
      for (int j = 0; j < NH; ++j) lg += sh_t[j * 8 + r] * gw2[j * NK + k];
      float m = lg;
      for (int off = 1; off < 16; off <<= 1) m = fmaxf(m, __shfl_xor(m, off, 16));
      float e = __builtin_amdgcn_exp2f((lg - m) * 1.44269504f);
      float s = e;
      for (int off = 1; off < 16; off <<= 1) s += __shfl_xor(s, off, 16);
      gates[(b0 + r) * NK + k] = e * __builtin_amdgcn_rcpf(s);
    }
  }
}

// ------------------------------------------------------------------ GEMM ----
// M-tile 512 (8 waves x 64 rows), N-tile 128. B staged in LDS in two 64KB
// halves (XOR-swizzled for conflict-free ds_read_b128); A streamed direct to
// VGPR in MFMA lane layout (1KB-contiguous per instr) with 2-deep ring
// prefetch. 32 MFMA per kk per wave -> LDS BW and load latency both covered.
__global__ __launch_bounds__(512, 2) void k_gemm(
    const unsigned short* __restrict__ A2,    // [K*16][4096][32]
    const unsigned short* __restrict__ B2,    // [K*16][512][32]
    const float* __restrict__ b2,             // [K][512]
    unsigned short* __restrict__ h2bf) {      // [K][B][512]
  __shared__ __align__(16) unsigned short Bs[8 * 128 * 32];  // 64 KB
  const int t = threadIdx.x;
  const int l = t & 63;
  const int w = t >> 6;                       // wave 0..7
  // XCD-phase mapping: first all even experts (one 4MB A-slice per XCD L2),
  // then odd. 512 blocks: xcd = lin&7, 32 CUs/XCD, 1 block/CU.
  const int lin = blockIdx.x;
  const int xcd = lin & 7;
  const int slot = lin >> 3;                  // 0..63
  const int ke = xcd * 2 + (slot >> 5);       // 0..15
  const int rem = slot & 31;
  const int m0 = (rem >> 2) * 512;            // 8 m-blocks
  const int n0 = (rem & 3) * 128;             // 4 n-blocks

  const int q = l >> 4, m16 = l & 15;

  // A lane base (ushort idx): rows (f*8+w)*16+m16 of tile; frag f adds 4096.
  const unsigned short* Abase =
      A2 + ((size_t)(ke * 16)) * (NB * 32) + (m0 + w * 16 + m16) * 32 + q * 8;

  // --- B staging: wave w stages kk_local = w (8KB) per half, swizzled ---
  auto stageB = [&](int h) {
    const int kkg = h * 8 + w;
    const char* src =
        (const char*)(B2 + (((size_t)(ke * 16 + kkg)) * ND + n0) * 32);
#pragma unroll
    for (int j = 0; j < 8; ++j) {
      int e_local = j * 16 + (l >> 2);
      int cg = ((l & 3) - (e_local >> 1)) & 3;  // global chunk for LDS slot l&3
      __builtin_amdgcn_global_load_lds(
          (const __attribute__((address_space(1))) void*)(src + (size_t)e_local * 64 + cg * 16),
          (__attribute__((address_space(3))) void*)&Bs[(w * 128 + j * 16) * 32],
          16, 0, 0);
    }
  };

  short8 Abuf[3][4];
  auto loadA = [&](int kk, int ring) {
#pragma unroll
    for (int f = 0; f < 4; ++f)
      Abuf[ring][f] = *(const short8*)(Abase + (size_t)kk * (NB * 32) + f * 4096);
  };

  loadA(0, 0);
  loadA(1, 1);
  stageB(0);
  __syncthreads();

  float4v acc[4][8];
#pragma unroll
  for (int f = 0; f < 4; ++f)
#pragma unroll
    for (int b = 0; b < 8; ++b) acc[f][b] = (float4v){0.f, 0.f, 0.f, 0.f};

#pragma unroll
  for (int h = 0; h < 2; ++h) {
    if (h == 1) {
      __syncthreads();   // all waves done reading half 0
      stageB(1);
      __syncthreads();   // half 1 staged
    }
#pragma unroll
    for (int kkl = 0; kkl < 8; ++kkl) {
      const int kk = h * 8 + kkl;
      if (kk + 2 < 16) loadA(kk + 2, (kk + 2) % 3);
      short8 bf[8];
#pragma unroll
      for (int bni = 0; bni < 8; ++bni) {
        int e_local = bni * 16 + m16;
        bf[bni] = *(const short8*)&Bs[(kkl * 128 + e_local) * 32 +
                                      (((q + (e_local >> 1)) & 3) * 8)];
      }
#pragma unroll
      for (int f = 0; f < 4; ++f)
#pragma unroll
        for (int bni = 0; bni < 8; ++bni)
          acc[f][bni] = __builtin_amdgcn_mfma_f32_16x16x32_bf16(
              Abuf[kk % 3][f], bf[bni], acc[f][bni], 0, 0, 0);
    }
  }

  // --- epilogue: +b2, tanh, bf16; 4 LDS-transpose passes reusing Bs ---
  unsigned short* sh2 = (unsigned short*)Bs;  // 128 x 136 ushorts = 34 KB
  const float* b2k = b2 + ke * ND;
  float biasv[8];
#pragma unroll
  for (int bni = 0; bni < 8; ++bni) biasv[bni] = b2k[n0 + bni * 16 + m16];

#pragma unroll
  for (int p = 0; p < 4; ++p) {
    __syncthreads();  // safe to (over)write LDS
#pragma unroll
    for (int bni = 0; bni < 8; ++bni) {
      int col = bni * 16 + m16;
#pragma unroll
      for (int rr = 0; rr < 4; ++rr) {
        int row_local = w * 16 + q * 4 + rr;  // frag f=p rows: (p*8+w)*16+...
        sh2[row_local * 136 + col] = f2bf(fast_tanh(acc[p][bni][rr] + biasv[bni]));
      }
    }
    __syncthreads();
    unsigned short* Ob = h2bf + ((size_t)ke * NB + m0 + p * 128) * ND + n0;
#pragma unroll
    for (int it = 0; it < 4; ++it) {
      int row = t >> 2;
      int col = ((t & 3) + it * 4) * 8;
      *(uint4*)&Ob[(size_t)row * ND + col] = *(uint4*)&sh2[row * 136 + col];
    }
  }
}

// -------------------------------------------------- LN + gate-mix + final ----
__global__ __launch_bounds__(256) void k_final(
    const unsigned short* __restrict__ h2bf,  // [K][B][512]
    const float* __restrict__ gates,          // [B][16]
    const float* __restrict__ x_l,            // [B][8]
    const float* __restrict__ ln_g, const float* __restrict__ ln_b,
    const float* __restrict__ theta0,         // [512]
    float* __restrict__ out) {
  const int t = threadIdx.x;
  const int l = t & 63;
  const int b = blockIdx.x * 4 + (t >> 6);
  const int d0 = l * 8;
  float g[8], bb[8], t0[8], acc[8];
  *(float4*)&g[0] = *(const float4*)&ln_g[d0];
  *(float4*)&g[4] = *(const float4*)&ln_g[d0 + 4];
  *(float4*)&bb[0] = *(const float4*)&ln_b[d0];
  *(float4*)&bb[4] = *(const float4*)&ln_b[d0 + 4];
  *(float4*)&t0[0] = *(const float4*)&theta0[d0];
  *(float4*)&t0[4] = *(const float4*)&theta0[d0 + 4];
#pragma unroll
  for (int j = 0; j < 8; ++j) acc[j] = 0.f;
  const float xl = x_l[b * 8 + (l >> 3)];

  for (int k = 0; k < NK; ++k) {
    uint4 raw = *(const uint4*)&h2bf[((size_t)k * NB + b) * ND + d0];
    const unsigned short* hp = (const unsigned short*)&raw;
    float v[8];
#pragma unroll
    for (int j = 0; j < 8; ++j) v[j] = bf2f(hp[j]);
    float s = 0.f, s2 = 0.f;
#pragma unroll
    for (int j = 0; j < 8; ++j) { s += v[j]; s2 += v[j] * v[j]; }
    for (int off = 1; off < 64; off <<= 1) {
      s += __shfl_xor(s, off, 64);
      s2 += __shfl_xor(s2, off, 64);
    }
    float mu = s * (1.f / 512.f);
    float var = s2 * (1.f / 512.f) - mu * mu;
    float rs = __builtin_amdgcn_rsqf(var + 1e-5f);
    float gate = gates[b * NK + k];
#pragma unroll
    for (int j = 0; j < 8; ++j) acc[j] += gate * ((v[j] - mu) * rs * g[j] + bb[j]);
  }
  float th[8];
#pragma unroll
  for (int j = 0; j < 8; ++j) th[j] = acc[j] + t0[j];
  float* thp = out + (size_t)NB * 64 + (size_t)b * ND + d0;
  *(float4*)&thp[0] = *(float4*)&th[0];
  *(float4*)&thp[4] = *(float4*)&th[4];
  float p[8];
#pragma unroll
  for (int j = 0; j < 8; ++j) p[j] = xl * th[j];
  for (int off = 8; off < 64; off <<= 1)
#pragma unroll
    for (int j = 0; j < 8; ++j) p[j] += __shfl_xor(p[j], off, 64);
  if (l < 8) {
    float* xp = out + (size_t)b * 64 + l * 8;
    *(float4*)&xp[0] = *(float4*)&p[0];
    *(float4*)&xp[4] = *(float4*)&p[4];
  }
}

// ----------------------------------------------------------------- launch ----
extern "C" void kernel_launch(void* const* d_in, const int* in_sizes, int n_in,
                              void* d_out, int out_size, void* d_ws, size_t ws_size,
                              hipStream_t stream) {
  const float* h_prev = (const float*)d_in[0];
  const float* x_l    = (const float*)d_in[1];
  const float* x_ext  = (const float*)d_in[2];
  const float* mw1    = (const float*)d_in[3];
  const float* mb1    = (const float*)d_in[4];
  const float* mw2    = (const float*)d_in[5];
  const float* mb2    = (const float*)d_in[6];
  const float* gw1    = (const float*)d_in[7];
  const float* gb1    = (const float*)d_in[8];
  const float* gw2    = (const float*)d_in[9];
  const float* gb2    = (const float*)d_in[10];
  const float* ln_g   = (const float*)d_in[11];
  const float* ln_b   = (const float*)d_in[12];
  const float* th0    = (const float*)d_in[13];
  float* out = (float*)d_out;

  char* ws = (char*)d_ws;
  float* gates = (float*)ws;                                   // 256 KB
  unsigned short* A2 = (unsigned short*)(ws + (1u << 18));     // 64 MB
  unsigned short* B2 = (unsigned short*)(ws + (1u << 18) + (64u << 20));  // 8 MB
  unsigned short* h2bf = (unsigned short*)(ws + (1u << 18) + (72u << 20));  // 64 MB

  hipLaunchKernelGGL(k_prep, dim3(17920), dim3(256), 0, stream,
                     x_ext, mw1, mb1, mw2, h_prev, gw1, gb1, gw2, gb2,
                     A2, B2, gates);
  hipLaunchKernelGGL(k_gemm, dim3(512), dim3(512), 0, stream,
                     A2, B2, mb2, h2bf);
  hipLaunchKernelGGL(k_final, dim3(NB / 4), dim3(256), 0, stream,
                     h2bf, gates, x_l, ln_g, ln_b, th0, out);
}